// Round 1
// baseline (1269.615 us; speedup 1.0000x reference)
//
#include <hip/hip_runtime.h>

// ElmanRNN: BATCH=4096, SEQ=512, IN=2, HID=128, OUT=1
// h_{t+1} = tanh(x_t @ Wx^T + h_t @ Wh^T + b_ih);  out = h_S @ Who^T + b_ho
//
// One kernel launch. 512 blocks x 256 threads; each block owns BT=8 batch rows
// and runs the full 512-step recurrence locally (batches independent).
// Thread (j = tid&127, g = tid>>7): holds W_h row j in 128 VGPRs (stationary
// across all steps), computes hidden unit j for 4 batch rows (g picks which 4).
// h ping-pongs in LDS; all h reads are wave-uniform broadcast ds_read_b128.

constexpr int BATCH   = 4096;
constexpr int SEQ     = 512;
constexpr int INP     = 2;
constexpr int HID     = 128;
constexpr int BT      = 8;    // batch rows per block
constexpr int THREADS = 256;  // 4 waves
constexpr int XCHUNK  = 64;   // time steps of x staged per chunk

__global__ __launch_bounds__(THREADS, 2)
void elman_rnn_kernel(const float* __restrict__ x,
                      const float* __restrict__ W_ih,
                      const float* __restrict__ b_ih,
                      const float* __restrict__ W_ho,
                      const float* __restrict__ b_ho,
                      float* __restrict__ out)
{
    __shared__ float hbuf[2][BT][HID];        // 8 KB: ping-pong hidden state
    __shared__ float xs[BT][XCHUNK * INP];    // 4 KB: staged x chunk

    const int tid = threadIdx.x;
    const int j   = tid & (HID - 1);   // hidden unit owned by this thread
    const int g   = tid >> 7;          // 0/1: which half of the 8 batch rows
    const int b0g = g * 4;             // first local batch row (4 rows each)
    const int blockB0 = blockIdx.x * BT;

    // ---- load weights for hidden unit j (stationary in registers) ----
    const float* Wrow = W_ih + (size_t)j * (INP + HID);
    const float wx0 = Wrow[0];
    const float wx1 = Wrow[1];
    const float bj  = b_ih[j];
    float4 Wr[HID / 4];                // 128 VGPRs of W_h row j
    #pragma unroll
    for (int q = 0; q < HID / 4; ++q) {
        Wr[q].x = Wrow[INP + 4 * q + 0];
        Wr[q].y = Wrow[INP + 4 * q + 1];
        Wr[q].z = Wrow[INP + 4 * q + 2];
        Wr[q].w = Wrow[INP + 4 * q + 3];
    }

    // ---- h0 = 0 ----
    #pragma unroll
    for (int bi = 0; bi < 4; ++bi)
        hbuf[0][b0g + bi][j] = 0.0f;   // g=0 covers rows 0-3, g=1 rows 4-7

    const int xrow = tid >> 5;         // 0..7  (batch row for x staging)
    const int xcol = (tid & 31) * 4;   // 0..124 (float4 column)

    int cur = 0;
    #pragma unroll 1
    for (int t0 = 0; t0 < SEQ; t0 += XCHUNK) {
        // stage x[blockB0+row][t0 .. t0+XCHUNK-1][:] -> xs (coalesced float4)
        // previous end-of-step barrier (or nothing at t0=0) guarantees xs free
        *reinterpret_cast<float4*>(&xs[xrow][xcol]) =
            *reinterpret_cast<const float4*>(
                x + (size_t)(blockB0 + xrow) * (SEQ * INP) + (size_t)t0 * INP + xcol);
        __syncthreads();  // xs + (first iter) h-init visible

        #pragma unroll 1
        for (int tt = 0; tt < XCHUNK; ++tt) {
            // pre-activation: bias + x-term (uniform scalar LDS reads)
            float acc[4];
            #pragma unroll
            for (int bi = 0; bi < 4; ++bi) {
                acc[bi] = fmaf(wx0, xs[b0g + bi][2 * tt],
                          fmaf(wx1, xs[b0g + bi][2 * tt + 1], bj));
            }

            // recurrent matvec: acc[bi] += sum_k Wh[j][k] * h[bi][k]
            const float4* h0 = reinterpret_cast<const float4*>(hbuf[cur][b0g + 0]);
            const float4* h1 = reinterpret_cast<const float4*>(hbuf[cur][b0g + 1]);
            const float4* h2 = reinterpret_cast<const float4*>(hbuf[cur][b0g + 2]);
            const float4* h3 = reinterpret_cast<const float4*>(hbuf[cur][b0g + 3]);
            #pragma unroll
            for (int q = 0; q < HID / 4; ++q) {
                const float4 w = Wr[q];
                float4 a;
                a = h0[q];
                acc[0] = fmaf(w.x, a.x, fmaf(w.y, a.y, fmaf(w.z, a.z, fmaf(w.w, a.w, acc[0]))));
                a = h1[q];
                acc[1] = fmaf(w.x, a.x, fmaf(w.y, a.y, fmaf(w.z, a.z, fmaf(w.w, a.w, acc[1]))));
                a = h2[q];
                acc[2] = fmaf(w.x, a.x, fmaf(w.y, a.y, fmaf(w.z, a.z, fmaf(w.w, a.w, acc[2]))));
                a = h3[q];
                acc[3] = fmaf(w.x, a.x, fmaf(w.y, a.y, fmaf(w.z, a.z, fmaf(w.w, a.w, acc[3]))));
            }

            // tanh + write h_new   (tanh(a) = 1 - 2/(exp(2a)+1); saturates ok)
            const int nxt = cur ^ 1;
            #pragma unroll
            for (int bi = 0; bi < 4; ++bi) {
                const float e  = __expf(2.0f * acc[bi]);
                const float hn = 1.0f - __fdividef(2.0f, e + 1.0f);
                hbuf[nxt][b0g + bi][j] = hn;
            }
            __syncthreads();
            cur = nxt;
        }
    }

    // ---- output projection: out[b] = Who . h_final[b] + b_ho ----
    if (tid < BT) {
        const int b = tid;
        float s = b_ho[0];
        const float* hr = hbuf[cur][b];
        #pragma unroll 8
        for (int k = 0; k < HID; ++k)
            s = fmaf(W_ho[k], hr[k], s);
        out[blockB0 + b] = s;
    }
}

extern "C" void kernel_launch(void* const* d_in, const int* in_sizes, int n_in,
                              void* d_out, int out_size, void* d_ws, size_t ws_size,
                              hipStream_t stream)
{
    (void)in_sizes; (void)n_in; (void)out_size; (void)d_ws; (void)ws_size;
    const float* x    = (const float*)d_in[0];
    const float* W_ih = (const float*)d_in[1];
    const float* b_ih = (const float*)d_in[2];
    const float* W_ho = (const float*)d_in[3];
    const float* b_ho = (const float*)d_in[4];
    float* out = (float*)d_out;

    dim3 grid(BATCH / BT);
    dim3 block(THREADS);
    elman_rnn_kernel<<<grid, block, 0, stream>>>(x, W_ih, b_ih, W_ho, b_ho, out);
}